// Round 4
// baseline (157.608 us; speedup 1.0000x reference)
//
#include <hip/hip_runtime.h>

#define BSZ   2
#define LSEQ  2048
#define DQ    512
#define SQ    4
#define EPSQ  1e-6f

typedef float nfloat4 __attribute__((ext_vector_type(4)));  // native vec for nontemporal
typedef float nfloat2 __attribute__((ext_vector_type(2)));  // VOP3P packed pair

__device__ __forceinline__ nfloat2 mk2(float x, float y) { nfloat2 v; v.x = x; v.y = y; return v; }

// ---------------- packed quaternion (pairs (r,i),(j,k); v_pk_fma_f32 path) ---
struct PQuat { nfloat2 ri, jk; };

__device__ __forceinline__ PQuat pq_of(const float4 v) {
    PQuat p; p.ri = mk2(v.x, v.y); p.jk = mk2(v.z, v.w); return p;
}
__device__ __forceinline__ float4 f4_of(const PQuat p) {
    return make_float4(p.ri.x, p.ri.y, p.jk.x, p.jk.y);
}

// o = a x b  (8 packed mul/fma vs 16 scalar)
__device__ __forceinline__ PQuat pqmul(const PQuat a, const PQuat b) {
    const float ar = a.ri.x, ai = a.ri.y, aj = a.jk.x, ak = a.jk.y;
    PQuat o;
    o.ri = ar*b.ri + ai*mk2(-b.ri.y,  b.ri.x)
         + aj*mk2(-b.jk.x,  b.jk.y) + ak*mk2(-b.jk.y, -b.jk.x);
    o.jk = ar*b.jk + ai*mk2(-b.jk.y,  b.jk.x)
         + aj*mk2( b.ri.x, -b.ri.y) + ak*mk2( b.ri.y,  b.ri.x);
    return o;
}

// o = a x b + c
__device__ __forceinline__ PQuat pqmuladd(const PQuat a, const PQuat b, const PQuat c) {
    const float ar = a.ri.x, ai = a.ri.y, aj = a.jk.x, ak = a.jk.y;
    PQuat o;
    o.ri = c.ri + ar*b.ri + ai*mk2(-b.ri.y,  b.ri.x)
         + aj*mk2(-b.jk.x,  b.jk.y) + ak*mk2(-b.jk.y, -b.jk.x);
    o.jk = c.jk + ar*b.jk + ai*mk2(-b.jk.y,  b.jk.x)
         + aj*mk2( b.ri.x, -b.ri.y) + ak*mk2( b.ri.y,  b.ri.x);
    return o;
}

// Precomputed per-(d,s) A-quaternion state (hA = 0.5*dt-free part).
struct HA { float r, i; nfloat2 jk; float p2, n2r; };

__device__ __forceinline__ HA load_hA(const float* __restrict__ Alog,
                                      const float* __restrict__ Ai,
                                      const float* __restrict__ Aj,
                                      const float* __restrict__ Ak, int idx) {
    HA h;
    h.r  = -0.5f * __expf(Alog[idx]);
    h.i  =  0.5f * Ai[idx];
    h.jk = mk2(0.5f * Aj[idx], 0.5f * Ak[idx]);
    h.p2 = h.r*h.r + h.i*h.i + h.jk.x*h.jk.x + h.jk.y*h.jk.y;
    h.n2r = -2.0f * h.r;
    return h;
}

// Cayley transition q and injection Bu (packed, strength-reduced).
__device__ __forceinline__ void cayley_pk(const float a, const float aa, const HA& hA,
                                          const PQuat B, const PQuat U,
                                          PQuat& q, PQuat& Bu) {
    const float dd = __builtin_fmaf(aa, hA.p2, __builtin_fmaf(a, hA.n2r, 1.0f + EPSQ));
    const float sv = __builtin_amdgcn_rcpf(dd);
    const float nr = __builtin_fmaf(-aa, hA.p2, 1.0f);   // 1 - |w|^2
    const float as = a * sv;
    const float s2a = as + as;                            // 2*a*s
    q.ri = mk2(nr * sv, s2a * hA.i);
    q.jk = s2a * hA.jk;
    PQuat cd;                                             // conj(den) = (1-wr, w_im)
    cd.ri = mk2(__builtin_fmaf(-a, hA.r, 1.0f), a * hA.i);
    cd.jk = a * hA.jk;
    const PQuat cb = pqmul(cd, B);
    PQuat dB; dB.ri = as * cb.ri; dB.jk = as * cb.jk;
    Bu = pqmul(dB, U);
}

// ---------------- scalar quat (pass2 only) -----------------------------------
struct Quat { float r, i, j, k; };
__device__ __forceinline__ Quat qmul(const Quat a, const Quat b) {
    Quat o;
    o.r = a.r*b.r - a.i*b.i - a.j*b.j - a.k*b.k;
    o.i = a.r*b.i + a.i*b.r + a.j*b.k - a.k*b.j;
    o.j = a.r*b.j - a.i*b.k + a.j*b.r + a.k*b.i;
    o.k = a.r*b.k + a.i*b.j - a.j*b.i + a.k*b.r;
    return o;
}
__device__ __forceinline__ Quat qmuladd(const Quat a, const Quat b, const Quat c) {
    Quat o;
    o.r = c.r + a.r*b.r - a.i*b.i - a.j*b.j - a.k*b.k;
    o.i = c.i + a.r*b.i + a.i*b.r + a.j*b.k - a.k*b.j;
    o.j = c.j + a.r*b.j - a.i*b.k + a.j*b.r + a.k*b.i;
    o.k = c.k + a.r*b.k + a.i*b.j - a.j*b.i + a.k*b.r;
    return o;
}
__device__ __forceinline__ Quat q_of(const float4 v) { return Quat{v.x, v.y, v.z, v.w}; }
__device__ __forceinline__ float4 f4s_of(const Quat q) { return make_float4(q.r, q.i, q.j, q.k); }

// ---------------- async global->LDS staging helpers --------------------------
// HW contract (m03/m97/m104): LDS dest = wave-uniform base + lane*size;
// global src is per-lane. size literal 16 or 4.
typedef unsigned int u32_t;
__device__ __forceinline__ void gl_lds16(const void* g, void* l) {
    __builtin_amdgcn_global_load_lds(
        (const __attribute__((address_space(1))) u32_t*)g,
        (__attribute__((address_space(3))) u32_t*)l, 16, 0, 0);
}
__device__ __forceinline__ void gl_lds4(const void* g, void* l) {
    __builtin_amdgcn_global_load_lds(
        (const __attribute__((address_space(1))) u32_t*)g,
        (__attribute__((address_space(3))) u32_t*)l, 4, 0, 0);
}

// ---------------- pass 1: chunk summaries, LDS-staged, 1 s-channel/thread ----
// grid: (DQ/128, NCH, BSZ), block 512 (8 waves), launch_bounds(512,8) ->
// VGPR<=64, 4 blocks/CU = 32 waves/CU (HW max). Thread (dl = t&127, sq = t>>7)
// owns channel (d, sq). Whole chunk (u 16K + dt 4K + B 0.5K) staged async;
// u/dt shared by all 4 s-channels.
template<int NCH>
__global__ __launch_bounds__(512, 8) void qssm_pass1(
    const float* __restrict__ u, const float* __restrict__ dt,
    const float* __restrict__ Bin,
    const float* __restrict__ Alog, const float* __restrict__ Ai,
    const float* __restrict__ Aj,   const float* __restrict__ Ak,
    float4* __restrict__ WQ, float4* __restrict__ WB)
{
    constexpr int CH = LSEQ / NCH;     // 8 steps per chunk (NCH=256)
    constexpr int RPW = (CH + 7) / 8;  // rows per wave (8 waves)
    __shared__ float4 uL[CH][128];
    __shared__ float  dtL[CH][128];
    __shared__ float4 BL[CH][SQ];

    const int t    = threadIdx.x;
    const int lane = t & 63;
    const int wid  = t >> 6;           // 0..7
    const int dblk = blockIdx.x;
    const int c    = blockIdx.y;
    const int b    = blockIdx.z;
    const int t0   = c * CH;
    const int base = b*LSEQ + t0;

    // ---- stage chunk (async, no VGPR round-trip) ----
    const float4* ug  = (const float4*)u + (size_t)base*DQ + dblk*128;
    const float*  dtg = dt + (size_t)base*DQ + dblk*128;
    const float*  Bg  = Bin + (size_t)base*SQ*4;   // CH*SQ*4 floats contiguous
#pragma unroll
    for (int jj = 0; jj < RPW; ++jj) {             // 8 waves x RPW rows each
        const int j = wid*RPW + jj;
        if (j < CH) {
#pragma unroll
            for (int k = 0; k < 2; ++k) {
                gl_lds16(ug  + (size_t)j*DQ + k*64 + lane, &uL[j][k*64]);
                gl_lds4 (dtg + (size_t)j*DQ + k*64 + lane, &dtL[j][k*64]);
            }
        }
    }
    if (wid == 0) {
#pragma unroll
        for (int k = 0; k < (CH*SQ*4)/64; ++k)
            gl_lds4(Bg + k*64 + lane, ((float*)BL) + k*64);
    }

    const int dl = t & 127;
    const int sq = t >> 7;            // s-channel 0..3
    const int d  = dblk*128 + dl;

    const HA hA = load_hA(Alog, Ai, Aj, Ak, d*SQ + sq);

    __syncthreads();                  // drains vmcnt incl. global_load_lds

    PQuat Q, Bc;
    {   // peel j = 0 (summary starts at identity)
        const float a  = dtL[0][dl];
        const float aa = a * a;
        cayley_pk(a, aa, hA, pq_of(BL[0][sq]), pq_of(uL[0][dl]), Q, Bc);
    }
#pragma unroll
    for (int j = 1; j < CH; ++j) {
        const float a  = dtL[j][dl];
        const float aa = a * a;
        PQuat q, Bu;
        cayley_pk(a, aa, hA, pq_of(BL[j][sq]), pq_of(uL[j][dl]), q, Bu);
        Bc = pqmuladd(q, Bc, Bu);     // B' = q x B + Bu
        Q  = pqmul(q, Q);             // Q' = q x Q
    }
    const size_t idx = ((size_t)(b*SQ + sq)*NCH + c)*DQ + d;
    WQ[idx] = f4_of(Q);
    WB[idx] = f4_of(Bc);
}

// ---------------- pass 2: hierarchical scan (proven) -------------------------
template<int NCH>
__global__ __launch_bounds__(512) void qssm_pass2(
    const float4* __restrict__ WQ, float4* __restrict__ WB)
{
    constexpr int GS = 8;           // chunks per superchunk
    constexpr int NG = NCH / GS;    // superchunks per channel
    __shared__ float4 QL[NG][16];
    __shared__ float4 BL2[NG][16];
    __shared__ float4 HS[NG][16];

    const int t  = threadIdx.x;
    const int i  = t & 15;
    const int g  = t >> 4;
    const int bs = blockIdx.x >> 5;
    const int d  = (blockIdx.x & 31) * 16 + i;
    const size_t chbase = (size_t)bs * NCH * DQ + d;

    size_t idx = chbase + (size_t)(g * GS) * DQ;
    Quat Qa = q_of(WQ[idx]);
    Quat Ba = q_of(WB[idx]);
#pragma unroll
    for (int j = 1; j < GS; ++j) {
        idx += DQ;
        const Quat Qc = q_of(WQ[idx]);
        const Quat Bc = q_of(WB[idx]);
        Ba = qmuladd(Qc, Ba, Bc);
        Qa = qmul(Qc, Qa);
    }
    QL[g][i]  = f4s_of(Qa);
    BL2[g][i] = f4s_of(Ba);
    __syncthreads();

    if (t < 16) {
        Quat h{0.f, 0.f, 0.f, 0.f};
#pragma unroll
        for (int gg = 0; gg < NG; ++gg) {
            HS[gg][t] = f4s_of(h);
            h = qmuladd(q_of(QL[gg][t]), h, q_of(BL2[gg][t]));
        }
    }
    __syncthreads();

    Quat h = q_of(HS[g][i]);
    idx = chbase + (size_t)(g * GS) * DQ;
#pragma unroll
    for (int j = 0; j < GS; ++j) {
        const Quat Qc = q_of(WQ[idx]);
        const Quat Bc = q_of(WB[idx]);
        WB[idx] = f4s_of(h);
        h = qmuladd(Qc, h, Bc);
        idx += DQ;
    }
}

// ---------------- pass 3: replay, LDS-staged, 1 s-channel/thread -------------
// grid: (DQ/128, NCH, BSZ), block 512 (8 waves), launch_bounds(512,8).
// Wave lane layout: dl = lane&15 (16 d), sq = lane>>4 (4 s). y reduced across
// the 4 s-lanes via shfl_xor(16)+shfl_xor(32); lanes sq==0 store (16x16B=256B
// contiguous per wave).
template<int NCH>
__global__ __launch_bounds__(512, 8) void qssm_pass3(
    const float* __restrict__ u, const float* __restrict__ dt,
    const float* __restrict__ Bin, const float* __restrict__ Cin,
    const float* __restrict__ Alog, const float* __restrict__ Ai,
    const float* __restrict__ Aj,   const float* __restrict__ Ak,
    const float4* __restrict__ WB, float* __restrict__ out)
{
    constexpr int CH = LSEQ / NCH;
    constexpr int RPW = (CH + 7) / 8;
    __shared__ float4 uL[CH][128];
    __shared__ float  dtL[CH][128];
    __shared__ float4 BL[CH][SQ];
    __shared__ float4 CL[CH][SQ];

    const int t    = threadIdx.x;
    const int lane = t & 63;
    const int wid  = t >> 6;
    const int dblk = blockIdx.x;
    const int c    = blockIdx.y;
    const int b    = blockIdx.z;
    const int t0   = c * CH;
    const int base = b*LSEQ + t0;

    // ---- stage chunk ----
    const float4* ug  = (const float4*)u + (size_t)base*DQ + dblk*128;
    const float*  dtg = dt + (size_t)base*DQ + dblk*128;
    const float*  Bg  = Bin + (size_t)base*SQ*4;
    const float*  Cg  = Cin + (size_t)base*SQ*4;
#pragma unroll
    for (int jj = 0; jj < RPW; ++jj) {
        const int j = wid*RPW + jj;
        if (j < CH) {
#pragma unroll
            for (int k = 0; k < 2; ++k) {
                gl_lds16(ug  + (size_t)j*DQ + k*64 + lane, &uL[j][k*64]);
                gl_lds4 (dtg + (size_t)j*DQ + k*64 + lane, &dtL[j][k*64]);
            }
        }
    }
    if (wid == 0) {
#pragma unroll
        for (int k = 0; k < (CH*SQ*4)/64; ++k)
            gl_lds4(Bg + k*64 + lane, ((float*)BL) + k*64);
    } else if (wid == 1) {
#pragma unroll
        for (int k = 0; k < (CH*SQ*4)/64; ++k)
            gl_lds4(Cg + k*64 + lane, ((float*)CL) + k*64);
    }

    const int dl   = lane & 15;
    const int sq   = lane >> 4;            // s-channel 0..3
    const int dloc = wid*16 + dl;          // within-block d offset 0..127
    const int d    = dblk*128 + dloc;

    const HA hA = load_hA(Alog, Ai, Aj, Ak, d*SQ + sq);
    PQuat h = pq_of(WB[((size_t)(b*SQ + sq)*NCH + c)*DQ + d]);

    nfloat4* outp = (nfloat4*)out + (size_t)base*DQ + d;

    __syncthreads();

#pragma unroll
    for (int j = 0; j < CH; ++j) {
        const float a  = dtL[j][dloc];
        const float aa = a * a;
        PQuat q, Bu;
        cayley_pk(a, aa, hA, pq_of(BL[j][sq]), pq_of(uL[j][dloc]), q, Bu);
        h = pqmuladd(q, h, Bu);
        PQuat y = pqmul(pq_of(CL[j][sq]), h);
        // reduce partial y across the 4 s-lanes (xor 16 then 32)
        float yr = y.ri.x, yi = y.ri.y, yj = y.jk.x, yk = y.jk.y;
        yr += __shfl_xor(yr, 16); yi += __shfl_xor(yi, 16);
        yj += __shfl_xor(yj, 16); yk += __shfl_xor(yk, 16);
        yr += __shfl_xor(yr, 32); yi += __shfl_xor(yi, 32);
        yj += __shfl_xor(yj, 32); yk += __shfl_xor(yk, 32);
        if (sq == 0) {
            const nfloat4 yv = {yr, yi, yj, yk};
            __builtin_nontemporal_store(yv, outp);  // out never re-read
        }
        outp += DQ;
    }
}

// ======================= host launch =========================================
template<int NCH>
static void launch_all(const float* u, const float* dt, const float* Bin,
                       const float* Cin, const float* Alog, const float* Ai,
                       const float* Aj, const float* Ak,
                       float* out, void* d_ws, hipStream_t stream) {
    const size_t elems = (size_t)BSZ * SQ * NCH * DQ;
    float4* WQ = (float4*)d_ws;
    float4* WB = WQ + elems;
    dim3 g1(DQ / 128, NCH, BSZ);
    qssm_pass1<NCH><<<g1, 512, 0, stream>>>(u, dt, Bin, Alog, Ai, Aj, Ak, WQ, WB);
    qssm_pass2<NCH><<<(BSZ*SQ*DQ)/16, 16*(NCH/8), 0, stream>>>(WQ, WB);
    dim3 g3(DQ / 128, NCH, BSZ);
    qssm_pass3<NCH><<<g3, 512, 0, stream>>>(u, dt, Bin, Cin, Alog, Ai, Aj, Ak, WB, out);
}

extern "C" void kernel_launch(void* const* d_in, const int* in_sizes, int n_in,
                              void* d_out, int out_size, void* d_ws, size_t ws_size,
                              hipStream_t stream) {
    const float* u    = (const float*)d_in[0];
    const float* dt   = (const float*)d_in[1];
    const float* Bin  = (const float*)d_in[2];
    const float* Cin  = (const float*)d_in[3];
    const float* Alog = (const float*)d_in[4];
    const float* Ai   = (const float*)d_in[5];
    const float* Aj   = (const float*)d_in[6];
    const float* Ak   = (const float*)d_in[7];
    float* out = (float*)d_out;

    auto ws_need = [](int nch) -> size_t {
        return 2ull * BSZ * SQ * (size_t)nch * DQ * sizeof(float4);
    };
    if (ws_size >= ws_need(256)) {
        launch_all<256>(u, dt, Bin, Cin, Alog, Ai, Aj, Ak, out, d_ws, stream);
    } else if (ws_size >= ws_need(128)) {
        launch_all<128>(u, dt, Bin, Cin, Alog, Ai, Aj, Ak, out, d_ws, stream);
    } else {
        launch_all<64>(u, dt, Bin, Cin, Alog, Ai, Aj, Ak, out, d_ws, stream);
    }
}